// Round 3
// baseline (421.251 us; speedup 1.0000x reference)
//
#include <hip/hip_runtime.h>
#include <math.h>

// ---------------- model constants (double-precision derivation, f32 use) ----
static constexpr double dTS    = 1.0 / 44100.0;
static constexpr double dCM    = 12.5e-12;
static constexpr double dK     = dTS / dCM;              // Ts/CM
static constexpr double dGKF   = 19.8e-9;
static constexpr double dGKS   = 19.8e-9;
static constexpr double dEKF   = -71e-3;
static constexpr double dEKS   = -78e-3;
static constexpr double dEP    = 90e-3;
static constexpr double dGMET  = 30e-9;
static constexpr double dSCALE = 5.623413251903491e-06;  // 10^(-105/20)
static constexpr double dX0    = 20e-9;
static constexpr double dS0    = 16e-9;
static constexpr double dS1    = 35e-9;
static constexpr double dL2E   = 1.4426950408889634;     // log2(e)

// G = GMET / (1 + e^{z/S1}(1+e^{z/S0})),  z = X0 - SCALE*x
//   = GMET / (1 + 2^{K1*x+C1} + 2^{K2*x+C2})   (exp2-fused, one fma per exp)
static constexpr float F_K1   = (float)(-dSCALE / dS1 * dL2E);
static constexpr float F_C1   = (float)( dX0    / dS1 * dL2E);
static constexpr float F_K2   = (float)(-dSCALE * (1.0/dS1 + 1.0/dS0) * dL2E);
static constexpr float F_C2   = (float)( dX0    * (1.0/dS1 + 1.0/dS0) * dL2E);
static constexpr float F_ANOG = (float)(1.0 - (dGKF + dGKS) * dK);
static constexpr float F_GMK  = (float)(dGMET * dK);
static constexpr float F_EP   = (float)dEP;
static constexpr float F_C0   = (float)(dEP + (dGKF*(dEKF-dEP) + dGKS*(dEKS-dEP)) * dK);

constexpr int T_LEN = 131072;   // time samples per lane
constexpr int SEG   = 8192;     // samples per segment (one LDS staging round)
constexpr int NSEG  = 4;        // segments per block (exact state carry between)
constexpr int GROUP = SEG * NSEG;   // 32768 samples per block
constexpr int WARM  = 256;      // a<=0.9282 -> a^256 ~ 5.7e-9: converged
constexpr int SPT   = 32;       // samples per thread per segment
constexpr int NTH   = 256;

typedef float v4f __attribute__((ext_vector_type(4)));

// Barrier with LDS visibility but NO vmcnt drain: keeps register-prefetch
// loads and previous segment's nontemporal stores in flight.
// (__syncthreads would emit s_waitcnt vmcnt(0) and serialize the pipeline.)
__device__ __forceinline__ void bar_lds() {
    asm volatile("s_waitcnt lgkmcnt(0)\n\ts_barrier" ::: "memory");
}

// MET conductance -> recurrence coefficient a = 1 - (G+GKF+GKS)*Ts/CM
__device__ __forceinline__ float coef(float xv) {
    float e1  = __builtin_amdgcn_exp2f(fmaf(F_K1, xv, F_C1));
    float e2  = __builtin_amdgcn_exp2f(fmaf(F_K2, xv, F_C2));
    float den = 1.0f + e1 + e2;                   // inf-safe -> rcp = 0
    return fmaf(-F_GMK, __builtin_amdgcn_rcpf(den), F_ANOG);
}

__global__ __launch_bounds__(NTH, 5) void ihc_kernel(const float* __restrict__ x,
                                                     float* __restrict__ out,
                                                     float vpre) {
    const int c = blockIdx.x;                     // segment-group 0..3
    const int l = blockIdx.y;                     // lane 0..399
    const int t = threadIdx.x;
    const long lbase = (long)l * T_LEN;
    const float* xg = x + lbase + (long)c * GROUP;
    float* og       = out + lbase + (long)c * GROUP;
    const int lane = t & 63;
    const int w    = t >> 6;
    const int s7   = t & 7;

    // 32 KB -> 5 blocks/CU. Reused per segment: 16-float scan scratch
    // (aliased into words 0..15) then swizzled output staging.
    __shared__ float lbuf[SEG];
    float4* lb4 = reinterpret_cast<float4*>(lbuf);

    // ---- segment-0 input (direct per-thread contiguous 32 floats) + warm
    float4 q[8];
    {
        const float4* qp = reinterpret_cast<const float4*>(xg + t * SPT);
#pragma unroll
        for (int j = 0; j < 8; ++j) q[j] = qp[j];
    }
    const float wx = xg[t + ((c == 0) ? 0 : -WARM)];
    float aw = coef(wx);
    float bw = fmaf(-F_EP, aw, F_C0);
    if (c == 0) { aw = 1.0f; bw = 0.0f; }         // group 0 starts exactly at vpre

    float vseg = vpre;                            // state entering current segment

#pragma unroll
    for (int s = 0; s < NSEG; ++s) {
        // ---- prefetch next segment's inputs (in flight through this segment)
        float4 qn[8];
        if (s < NSEG - 1) {
            const float4* qp = reinterpret_cast<const float4*>(xg + (s + 1) * SEG + t * SPT);
#pragma unroll
            for (int j = 0; j < 8; ++j) qn[j] = qp[j];
        }

        // ---- pass 1: coefficients + local affine composition (A,B)
        float A = 1.0f, B = 0.0f;
#pragma unroll
        for (int j = 0; j < 8; ++j) {
            float ev[4] = {q[j].x, q[j].y, q[j].z, q[j].w};
#pragma unroll
            for (int i = 0; i < 4; ++i) {
                float a = coef(ev[i]);
                float b = fmaf(-F_EP, a, F_C0);
                B = fmaf(a, B, b);
                A = A * a;
                ev[i] = a;
            }
            q[j] = make_float4(ev[0], ev[1], ev[2], ev[3]);
        }

        // ---- intra-wave inclusive scan (warm interleaved only in segment 0)
        if (s == 0) {
#pragma unroll
            for (int d = 1; d < 64; d <<= 1) {
                float pa  = __shfl_up(A,  d, 64);
                float pb  = __shfl_up(B,  d, 64);
                float pwa = __shfl_up(aw, d, 64);
                float pwb = __shfl_up(bw, d, 64);
                if (lane >= d) {
                    B  = fmaf(A,  pb,  B);  A  *= pa;
                    bw = fmaf(aw, pwb, bw); aw *= pwa;
                }
            }
        } else {
#pragma unroll
            for (int d = 1; d < 64; d <<= 1) {
                float pa = __shfl_up(A, d, 64);
                float pb = __shfl_up(B, d, 64);
                if (lane >= d) { B = fmaf(A, pb, B); A *= pa; }
            }
        }

        bar_lds();   // B0: prev segment's E-reads done before scratch overwrite
        if (lane == 63) {
            if (s == 0) { lbuf[w] = aw; lbuf[4 + w] = bw; }  // warm wave totals
            lbuf[8 + w] = A; lbuf[12 + w] = B;               // main wave totals
        }
        bar_lds();   // B1: scratch visible

        // warm total (segment 0 only), exclusive wave prefix, and full total
        float wA = 1.0f, wB = 0.0f;
        if (s == 0) {
#pragma unroll
            for (int i = 0; i < 4; ++i) { wB = fmaf(lbuf[i], wB, lbuf[4 + i]); wA *= lbuf[i]; }
        }
        float eA = 1.0f, eB = 0.0f;
        for (int i = 0; i < w; ++i) { eB = fmaf(lbuf[8 + i], eB, lbuf[12 + i]); eA *= lbuf[8 + i]; }
        float At = eA, Bt = eB;                   // continue to full-block total
        for (int i = w; i < 4; ++i) { Bt = fmaf(lbuf[8 + i], Bt, lbuf[12 + i]); At *= lbuf[8 + i]; }

        float sa = __shfl_up(A, 1, 64);
        float sb = __shfl_up(B, 1, 64);
        if (lane == 0) { sa = 1.0f; sb = 0.0f; }

        const float vw = (s == 0) ? fmaf(wA, vseg, wB) : vseg;  // state at seg start
        float u = fmaf(eA, vw, eB);               // state at wave start
        float v = fmaf(sa, u, sb);                // state at this thread's run
        vseg = fmaf(At, vw, Bt);                  // EXACT carry to next segment

        bar_lds();   // B2: scratch reads done before D overwrites words 0..15

        // ---- Phase D: replay recurrence, XOR-swizzled LDS writes
        // (logical group t*8+j stored at t*8+(j^(t&7)): conflict-free both sides)
#pragma unroll
        for (int j = 0; j < 8; ++j) {
            float ev[4] = {q[j].x, q[j].y, q[j].z, q[j].w};
            float ov[4];
#pragma unroll
            for (int i = 0; i < 4; ++i) {
                float a = ev[i];
                float b = fmaf(-F_EP, a, F_C0);
                v = fmaf(a, v, b);
                ov[i] = v - vpre;
            }
            lb4[t * 8 + (j ^ s7)] = make_float4(ov[0], ov[1], ov[2], ov[3]);
        }
        bar_lds();   // B3: output staged

        // ---- Phase E: swizzled LDS read -> coalesced nontemporal stores
        float* ops = og + s * SEG;
#pragma unroll
        for (int j = 0; j < 8; ++j) {
            int g  = t + NTH * j;
            int gp = g ^ ((g >> 3) & 7);
            float4 o = lb4[gp];
            v4f ov = { o.x, o.y, o.z, o.w };
            __builtin_nontemporal_store(ov, reinterpret_cast<v4f*>(ops + 4 * g));
        }

        // rotate prefetch into place (register rename, no copies after unroll)
        if (s < NSEG - 1) {
#pragma unroll
            for (int j = 0; j < 8; ++j) q[j] = qn[j];
        }
    }
}

// 50 ms pre-charge relaxation, f32 forward Euler (matches reference dtype)
static float compute_vpre() {
    const float TsCM = (float)dK;
    float v = -57.03e-3f;
    for (int i = 0; i < 2205; ++i) {
        float Imet = 3.3514e-9f * (v - 0.09f);
        float Ik   = 19.8e-9f   * (v + 0.071f);
        float Is   = 19.8e-9f   * (v + 0.078f);
        v = v - (Imet + Ik + Is) * TsCM;
    }
    return v;
}

extern "C" void kernel_launch(void* const* d_in, const int* in_sizes, int n_in,
                              void* d_out, int out_size, void* d_ws, size_t ws_size,
                              hipStream_t stream) {
    const float* x = (const float*)d_in[0];
    float* out = (float*)d_out;
    const int lanes = in_sizes[0] / T_LEN;        // B*F = 400
    const int ngroups = T_LEN / GROUP;            // 4
    float vpre = compute_vpre();                  // deterministic scalar, graph-safe
    dim3 grid(ngroups, lanes);
    hipLaunchKernelGGL(ihc_kernel, grid, dim3(NTH), 0, stream, x, out, vpre);
}

// Round 4
// 409.733 us; speedup vs baseline: 1.0281x; 1.0281x over previous
//
#include <hip/hip_runtime.h>
#include <math.h>

// ---------------- model constants (double-precision derivation, f32 use) ----
static constexpr double dTS    = 1.0 / 44100.0;
static constexpr double dCM    = 12.5e-12;
static constexpr double dK     = dTS / dCM;              // Ts/CM
static constexpr double dGKF   = 19.8e-9;
static constexpr double dGKS   = 19.8e-9;
static constexpr double dEKF   = -71e-3;
static constexpr double dEKS   = -78e-3;
static constexpr double dEP    = 90e-3;
static constexpr double dGMET  = 30e-9;
static constexpr double dSCALE = 5.623413251903491e-06;  // 10^(-105/20)
static constexpr double dX0    = 20e-9;
static constexpr double dS0    = 16e-9;
static constexpr double dS1    = 35e-9;
static constexpr double dL2E   = 1.4426950408889634;     // log2(e)

// G = GMET / (1 + e^{z/S1}(1+e^{z/S0})),  z = X0 - SCALE*x
//   = GMET / (1 + 2^{K1*x+C1} + 2^{K2*x+C2})   (exp2-fused, one fma per exp)
static constexpr float F_K1   = (float)(-dSCALE / dS1 * dL2E);
static constexpr float F_C1   = (float)( dX0    / dS1 * dL2E);
static constexpr float F_K2   = (float)(-dSCALE * (1.0/dS1 + 1.0/dS0) * dL2E);
static constexpr float F_C2   = (float)( dX0    * (1.0/dS1 + 1.0/dS0) * dL2E);
static constexpr float F_ANOG = (float)(1.0 - (dGKF + dGKS) * dK);
static constexpr float F_GMK  = (float)(dGMET * dK);
static constexpr float F_EP   = (float)dEP;
static constexpr float F_C0   = (float)(dEP + (dGKF*(dEKF-dEP) + dGKS*(dEKS-dEP)) * dK);

constexpr int T_LEN = 131072;   // time samples per lane
constexpr int CHUNK = 8192;     // output samples per block
constexpr int HALF  = CHUNK / 2;// staging window (16 KB -> 8 blocks/CU)
constexpr int WARM  = 256;      // a<=0.9282 -> a^256 ~ 5.7e-9: converged
constexpr int SPT   = 32;       // samples per thread: 256*32 = 8192
constexpr int NTH   = 256;

typedef float v4f __attribute__((ext_vector_type(4)));

// MET conductance -> recurrence coefficient a = 1 - (G+GKF+GKS)*Ts/CM
__device__ __forceinline__ float coef(float xv) {
    float e1  = __builtin_amdgcn_exp2f(fmaf(F_K1, xv, F_C1));
    float e2  = __builtin_amdgcn_exp2f(fmaf(F_K2, xv, F_C2));
    float den = 1.0f + e1 + e2;                   // inf-safe -> rcp = 0
    return fmaf(-F_GMK, __builtin_amdgcn_rcpf(den), F_ANOG);
}

// 16 KB LDS + VGPR<=64 -> 8 blocks/CU = 32 waves/CU (100% occupancy).
__global__ __launch_bounds__(NTH, 8) void ihc_kernel(const float* __restrict__ x,
                                                     float* __restrict__ out,
                                                     float vpre) {
    const int c = blockIdx.x;                     // chunk index 0..15
    const int l = blockIdx.y;                     // lane index 0..399
    const int t = threadIdx.x;
    const long lbase = (long)l * T_LEN;
    const float* xp  = x + lbase + (long)c * CHUNK;
    float* opc       = out + lbase + (long)c * CHUNK;
    const int lane = t & 63;
    const int w    = t >> 6;

    // 16 KB staging, reused: 16-float scan scratch (aliased), then two
    // rounds of swizzled output staging (samples 0..4095, then 4096..8191).
    __shared__ float lbuf[HALF];
    float4* lb4 = reinterpret_cast<float4*>(lbuf);

    // ---- input: 8 aligned float4 per thread (contiguous 32 floats)
    float4 q[8];
    {
        const float4* qp = reinterpret_cast<const float4*>(xp + t * SPT);
#pragma unroll
        for (int j = 0; j < 8; ++j) q[j] = qp[j];
    }
    // warm-up input: ONE sample per thread (coalesced 1 KB just before chunk)
    const float wx = xp[t + ((c == 0) ? 0 : -WARM)];
    float aw = coef(wx);
    float bw = fmaf(-F_EP, aw, F_C0);
    if (c == 0) { aw = 1.0f; bw = 0.0f; }         // chunk 0 starts exactly at vpre

    // ---- pass 1: per-element coefficient + local affine composition (A,B)
    float A = 1.0f, B = 0.0f;
#pragma unroll
    for (int j = 0; j < 8; ++j) {
        float ev[4] = {q[j].x, q[j].y, q[j].z, q[j].w};
#pragma unroll
        for (int i = 0; i < 4; ++i) {
            float a = coef(ev[i]);
            float b = fmaf(-F_EP, a, F_C0);
            B = fmaf(a, B, b);
            A = A * a;
            ev[i] = a;
        }
        q[j] = make_float4(ev[0], ev[1], ev[2], ev[3]);
    }

    // ---- interleaved intra-wave inclusive scans (warm + main share steps)
#pragma unroll
    for (int d = 1; d < 64; d <<= 1) {
        float pa  = __shfl_up(A,  d, 64);
        float pb  = __shfl_up(B,  d, 64);
        float pwa = __shfl_up(aw, d, 64);
        float pwb = __shfl_up(bw, d, 64);
        if (lane >= d) {
            B  = fmaf(A,  pb,  B);  A  *= pa;
            bw = fmaf(aw, pwb, bw); aw *= pwa;
        }
    }

    // wave totals -> scratch (first touch of lbuf)
    if (lane == 63) {
        lbuf[w]      = aw;  lbuf[4 + w]  = bw;    // warm wave totals
        lbuf[8 + w]  = A;   lbuf[12 + w] = B;     // main wave totals
    }
    __syncthreads();                              // S1: scratch visible

    // warm total = compose all 4 wave segments (time order)
    float wA = 1.0f, wB = 0.0f;
#pragma unroll
    for (int i = 0; i < 4; ++i) { wB = fmaf(lbuf[i], wB, lbuf[4 + i]); wA *= lbuf[i]; }
    // main exclusive prefix across waves
    float eA = 1.0f, eB = 0.0f;
    for (int i = 0; i < w; ++i) { eB = fmaf(lbuf[8 + i], eB, lbuf[12 + i]); eA *= lbuf[8 + i]; }
    float sa = __shfl_up(A, 1, 64);
    float sb = __shfl_up(B, 1, 64);
    if (lane == 0) { sa = 1.0f; sb = 0.0f; }

    float vw = fmaf(wA, vpre, wB);                // state after warm-up
    float u  = fmaf(eA, vw, eB);                  // state at wave start
    float v  = fmaf(sa, u, sb);                   // state at this thread's segment
    __syncthreads();                              // S2: scratch reads before D

    // ---- Phase D/E in two 16 KB rounds.
    // Round h: threads [128h,128h+128) own half-samples [4096h, 4096h+4096);
    // they replay their full 32-sample run into lb4 with the XOR involution
    // (logical group G=tt*8+j at G^((G>>3)&7) -> conflict-free both sides);
    // then ALL threads store the half contiguously (perfectly coalesced).
#pragma unroll
    for (int h = 0; h < 2; ++h) {
        if ((t >> 7) == h) {
            const int tt = t & 127;
            const int s7 = tt & 7;
#pragma unroll
            for (int j = 0; j < 8; ++j) {
                float ev[4] = {q[j].x, q[j].y, q[j].z, q[j].w};
                float ov[4];
#pragma unroll
                for (int i = 0; i < 4; ++i) {
                    float a = ev[i];
                    float b = fmaf(-F_EP, a, F_C0);
                    v = fmaf(a, v, b);
                    ov[i] = v - vpre;
                }
                lb4[tt * 8 + (j ^ s7)] = make_float4(ov[0], ov[1], ov[2], ov[3]);
            }
        }
        __syncthreads();                          // half staged

        float* oph = opc + h * HALF;
#pragma unroll
        for (int j = 0; j < 4; ++j) {
            int g  = t + NTH * j;                 // logical f4 group 0..1023
            int gp = g ^ ((g >> 3) & 7);          // same involution as D
            float4 o = lb4[gp];
            v4f ov = { o.x, o.y, o.z, o.w };
            __builtin_nontemporal_store(ov, reinterpret_cast<v4f*>(oph + 4 * g));
        }
        if (h == 0) __syncthreads();              // E-reads done before round 1
    }
}

// 50 ms pre-charge relaxation, f32 forward Euler (matches reference dtype)
static float compute_vpre() {
    const float TsCM = (float)dK;
    float v = -57.03e-3f;
    for (int i = 0; i < 2205; ++i) {
        float Imet = 3.3514e-9f * (v - 0.09f);
        float Ik   = 19.8e-9f   * (v + 0.071f);
        float Is   = 19.8e-9f   * (v + 0.078f);
        v = v - (Imet + Ik + Is) * TsCM;
    }
    return v;
}

extern "C" void kernel_launch(void* const* d_in, const int* in_sizes, int n_in,
                              void* d_out, int out_size, void* d_ws, size_t ws_size,
                              hipStream_t stream) {
    const float* x = (const float*)d_in[0];
    float* out = (float*)d_out;
    const int lanes = in_sizes[0] / T_LEN;        // B*F = 400
    const int nchunks = T_LEN / CHUNK;            // 16
    float vpre = compute_vpre();                  // deterministic scalar, graph-safe
    dim3 grid(nchunks, lanes);
    hipLaunchKernelGGL(ihc_kernel, grid, dim3(NTH), 0, stream, x, out, vpre);
}